// Round 2
// baseline (933.795 us; speedup 1.0000x reference)
//
#include <hip/hip_runtime.h>
#include <cstdint>
#include <cstddef>

#define BDIM 2
#define NQ 512
#define NEXP 256
#define MDIM 768
#define HN 48
#define DD 16
#define ED 768

// ---------------------------------------------------------------------------
// prep: wve[h][k] = sum_d w_force[h*16+d] * Wv[(h*16+d)*E + k]
//       ube[h]    = sum_d w_force[h*16+d] * bv[h*16+d]
// ---------------------------------------------------------------------------
__global__ void prep_kernel(const float* __restrict__ Wv, const float* __restrict__ bv,
                            const float* __restrict__ wf,
                            float* __restrict__ wve, float* __restrict__ ube) {
  int h = blockIdx.x;
  float wl[DD];
#pragma unroll
  for (int d = 0; d < DD; ++d) wl[d] = wf[h * DD + d];
  for (int k = threadIdx.x; k < ED; k += blockDim.x) {
    float s = 0.f;
#pragma unroll
    for (int d = 0; d < DD; ++d) s = fmaf(wl[d], Wv[(size_t)(h * DD + d) * ED + k], s);
    wve[(size_t)h * ED + k] = s;
  }
  if (threadIdx.x == 0) {
    float s = 0.f;
#pragma unroll
    for (int d = 0; d < DD; ++d) s = fmaf(wl[d], bv[h * DD + d], s);
    ube[h] = s;
  }
}

// ---------------------------------------------------------------------------
// proj: one GEMM out[1024 x 1584] = query[1024x768] @ [Wq; Wk; wve]^T
//   cols 0..767    -> qs[b][n][c]           = (dot + bq[c]) * 0.25
//   cols 768..1535 -> ke[(b*H+h)*16+d][n]   = dot + bk      (transposed k)
//   cols 1536..1583-> ub[(b*H+h)][n]        = dot + ube[h]
// ---------------------------------------------------------------------------
__global__ __launch_bounds__(256) void proj_kernel(
    const float* __restrict__ A,
    const float* __restrict__ Wq, const float* __restrict__ bq,
    const float* __restrict__ Wk, const float* __restrict__ bk,
    const float* __restrict__ wve, const float* __restrict__ ube,
    float* __restrict__ qs, float* __restrict__ ke, float* __restrict__ ub) {
  __shared__ __align__(16) float As[32][68];
  __shared__ __align__(16) float Bs[32][68];
  const int tid = threadIdx.x;
  const int tx = tid & 15, ty = tid >> 4;
  const int row0 = blockIdx.y * 64;
  const int col0 = blockIdx.x * 64;
  float acc[4][4] = {};
  for (int k0 = 0; k0 < ED; k0 += 32) {
    for (int f = tid; f < 512; f += 256) {
      int r = f >> 3, kq = f & 7;
      float4 v = *(const float4*)&A[(size_t)(row0 + r) * ED + k0 + kq * 4];
      As[kq * 4 + 0][r] = v.x; As[kq * 4 + 1][r] = v.y;
      As[kq * 4 + 2][r] = v.z; As[kq * 4 + 3][r] = v.w;
    }
    for (int f = tid; f < 512; f += 256) {
      int cc = f >> 3, kq = f & 7;
      int c = col0 + cc;
      float4 v = make_float4(0.f, 0.f, 0.f, 0.f);
      if (c < 1584) {
        const float* src;
        if (c < 768) src = Wq + (size_t)c * ED;
        else if (c < 1536) src = Wk + (size_t)(c - 768) * ED;
        else src = wve + (size_t)(c - 1536) * ED;
        v = *(const float4*)&src[k0 + kq * 4];
      }
      Bs[kq * 4 + 0][cc] = v.x; Bs[kq * 4 + 1][cc] = v.y;
      Bs[kq * 4 + 2][cc] = v.z; Bs[kq * 4 + 3][cc] = v.w;
    }
    __syncthreads();
#pragma unroll
    for (int kk = 0; kk < 32; ++kk) {
      float4 a4 = *(const float4*)&As[kk][ty * 4];
      float4 b4 = *(const float4*)&Bs[kk][tx * 4];
      float av[4] = {a4.x, a4.y, a4.z, a4.w};
      float bw[4] = {b4.x, b4.y, b4.z, b4.w};
#pragma unroll
      for (int i = 0; i < 4; ++i)
#pragma unroll
        for (int j = 0; j < 4; ++j) acc[i][j] = fmaf(av[i], bw[j], acc[i][j]);
    }
    __syncthreads();
  }
#pragma unroll
  for (int i = 0; i < 4; ++i) {
    int r = row0 + ty * 4 + i;
    int b = r >> 9, n = r & 511;
#pragma unroll
    for (int j = 0; j < 4; ++j) {
      int c = col0 + tx * 4 + j;
      if (c >= 1584) continue;
      float val = acc[i][j];
      if (c < 768) {
        qs[(size_t)(b * NQ + n) * ED + c] = (val + bq[c]) * 0.25f;
      } else if (c < 1536) {
        int ck = c - 768;
        int hh = ck >> 4, dd = ck & 15;
        ke[(size_t)((b * HN + hh) * DD + dd) * MDIM + n] = val + bk[ck];
      } else {
        int hh = c - 1536;
        ub[(size_t)(b * HN + hh) * MDIM + n] = val + ube[hh];
      }
    }
  }
}

// ---------------------------------------------------------------------------
// gather: fill m in [512,768) of ke / ub via outcell_index
// ---------------------------------------------------------------------------
__global__ void gather_kernel(const int* __restrict__ idx, float* __restrict__ ke,
                              float* __restrict__ ub) {
  const int id = blockIdx.x * 256 + threadIdx.x;
  const int N1 = BDIM * HN * DD * NEXP;  // 393216
  if (id < N1) {
    int j = id & (NEXP - 1);
    int d = (id >> 8) & (DD - 1);
    int hb = id >> 12;                   // b*48 + h, 0..95
    int n = idx[(hb / HN) * NEXP + j];
    float* row = ke + (size_t)(hb * DD + d) * MDIM;
    row[NQ + j] = row[n];
  } else {
    int id2 = id - N1;
    if (id2 < BDIM * HN * NEXP) {
      int j = id2 & (NEXP - 1);
      int hb = id2 >> 8;                 // b*48 + h
      int n = idx[(hb / HN) * NEXP + j];
      float* row = ub + (size_t)hb * MDIM;
      row[NQ + j] = row[n];
    }
  }
}

// ---------------------------------------------------------------------------
// attn: block = (b, h, 64-query tile). K read straight from L2 (no LDS, no
// barriers). Each wave does 4 query rows jointly (full m-row in registers),
// wave-shuffle softmax, then atomically accumulates W[b,n,m] += e*u/l.
// b == XCD parity (bid&1) so each XCD's L2 holds one b's K (2.3 MB < 4 MB).
// ---------------------------------------------------------------------------
__device__ __forceinline__ void fma4(float4& a, float q, const float4& k) {
  a.x = fmaf(q, k.x, a.x); a.y = fmaf(q, k.y, a.y);
  a.z = fmaf(q, k.z, a.z); a.w = fmaf(q, k.w, a.w);
}

__global__ __launch_bounds__(256, 4) void attn_kernel(
    const float* __restrict__ qs, const float* __restrict__ ke, const float* __restrict__ ub,
    const float* __restrict__ bias, float* __restrict__ W) {
  const int bid = blockIdx.x;
  const int b = bid & 1;
  const int r = bid >> 1;          // 0..383
  const int h = r % HN;
  const int t = r / HN;            // 0..7
  const int wave = threadIdx.x >> 6;
  const int lane = threadIdx.x & 63;

  const float* kbase = ke + (size_t)(b * HN + h) * DD * MDIM;
  const float4* u4 = (const float4*)(ub + (size_t)(b * HN + h) * MDIM);
  const float4 u0 = u4[lane], u1 = u4[lane + 64], u2 = u4[lane + 128];

  for (int it = 0; it < 4; ++it) {
    const int n0 = t * 64 + wave * 16 + it * 4;
    // bias rows for the 4 queries: 12 float4/lane, full m-row in registers
    float4 a[4][3];
#pragma unroll
    for (int qi = 0; qi < 4; ++qi) {
      const float4* bp = (const float4*)(bias + (size_t)((b * HN + h) * NQ + n0 + qi) * MDIM);
#pragma unroll
      for (int j = 0; j < 3; ++j) a[qi][j] = bp[lane + 64 * j];
    }
    // scores += q_d * K[d][m]   (K from global/L2; q loads wave-uniform)
#pragma unroll
    for (int x = 0; x < 4; ++x) {
      float4 qx[4];
#pragma unroll
      for (int qi = 0; qi < 4; ++qi)
        qx[qi] = ((const float4*)(qs + (size_t)(b * NQ + n0 + qi) * ED + h * DD))[x];
#pragma unroll
      for (int d4 = 0; d4 < 4; ++d4) {
        const int d = x * 4 + d4;
        const float4* kr = (const float4*)(kbase + (size_t)d * MDIM);
        const float4 k0 = kr[lane], k1 = kr[lane + 64], k2 = kr[lane + 128];
#pragma unroll
        for (int qi = 0; qi < 4; ++qi) {
          const float qd = (d4 == 0) ? qx[qi].x : (d4 == 1) ? qx[qi].y
                          : (d4 == 2) ? qx[qi].z : qx[qi].w;
          fma4(a[qi][0], qd, k0);
          fma4(a[qi][1], qd, k1);
          fma4(a[qi][2], qd, k2);
        }
      }
    }
#pragma unroll
    for (int qi = 0; qi < 4; ++qi) {
      float mx = -1e30f;
#pragma unroll
      for (int j = 0; j < 3; ++j)
        mx = fmaxf(mx, fmaxf(fmaxf(a[qi][j].x, a[qi][j].y), fmaxf(a[qi][j].z, a[qi][j].w)));
#pragma unroll
      for (int sh = 32; sh > 0; sh >>= 1) mx = fmaxf(mx, __shfl_xor(mx, sh));
      float e[12];
#pragma unroll
      for (int j = 0; j < 3; ++j) {
        e[j * 4 + 0] = __expf(a[qi][j].x - mx);
        e[j * 4 + 1] = __expf(a[qi][j].y - mx);
        e[j * 4 + 2] = __expf(a[qi][j].z - mx);
        e[j * 4 + 3] = __expf(a[qi][j].w - mx);
      }
      float l = 0.f;
#pragma unroll
      for (int k = 0; k < 12; ++k) l += e[k];
#pragma unroll
      for (int sh = 32; sh > 0; sh >>= 1) l += __shfl_xor(l, sh);
      const float inv = 1.0f / l;
      float* Wp = W + (size_t)(b * NQ + n0 + qi) * MDIM;
#pragma unroll
      for (int j = 0; j < 3; ++j) {
        const float4 uu = (j == 0) ? u0 : (j == 1) ? u1 : u2;
        const int m0 = j * 256 + lane * 4;
        atomicAdd(Wp + m0 + 0, e[j * 4 + 0] * uu.x * inv);
        atomicAdd(Wp + m0 + 1, e[j * 4 + 1] * uu.y * inv);
        atomicAdd(Wp + m0 + 2, e[j * 4 + 2] * uu.z * inv);
        atomicAdd(Wp + m0 + 3, e[j * 4 + 3] * uu.w * inv);
      }
    }
  }
}

// ---------------------------------------------------------------------------
// force: force[b,n,c] = sum_m W[b,n,m] * dp[b,n,m,c]. One wave per (b,n) row.
// ---------------------------------------------------------------------------
__global__ __launch_bounds__(256) void force_kernel(
    const float* __restrict__ W, const float* __restrict__ dp, float* __restrict__ out) {
  const int wave = threadIdx.x >> 6;
  const int lane = threadIdx.x & 63;
  const int row = blockIdx.x * 4 + wave;     // 0..1023 == b*512+n
  const float4* W4 = (const float4*)(W + (size_t)row * MDIM);
  const float* dpp = dp + (size_t)row * MDIM * 3;
  float f0 = 0.f, f1 = 0.f, f2 = 0.f;
#pragma unroll
  for (int j = 0; j < 3; ++j) {
    const float4 w = W4[lane + 64 * j];
    const int m0 = j * 256 + lane * 4;
    const float4* dv = (const float4*)(dpp + (size_t)m0 * 3);
    const float4 d0 = dv[0], d1 = dv[1], d2 = dv[2];
    f0 = fmaf(w.x, d0.x, f0); f0 = fmaf(w.y, d0.w, f0); f0 = fmaf(w.z, d1.z, f0); f0 = fmaf(w.w, d2.y, f0);
    f1 = fmaf(w.x, d0.y, f1); f1 = fmaf(w.y, d1.x, f1); f1 = fmaf(w.z, d1.w, f1); f1 = fmaf(w.w, d2.z, f1);
    f2 = fmaf(w.x, d0.z, f2); f2 = fmaf(w.y, d1.y, f2); f2 = fmaf(w.z, d2.x, f2); f2 = fmaf(w.w, d2.w, f2);
  }
#pragma unroll
  for (int sh = 32; sh > 0; sh >>= 1) {
    f0 += __shfl_xor(f0, sh);
    f1 += __shfl_xor(f1, sh);
    f2 += __shfl_xor(f2, sh);
  }
  if (lane == 0) {
    float* op = out + (size_t)row * 3;
    op[0] = f0; op[1] = f1; op[2] = f2;
  }
}

// ---------------------------------------------------------------------------
extern "C" void kernel_launch(void* const* d_in, const int* in_sizes, int n_in,
                              void* d_out, int out_size, void* d_ws, size_t ws_size,
                              hipStream_t stream) {
  const float* query     = (const float*)d_in[0];
  const float* attn_bias = (const float*)d_in[1];
  const float* delta_pos = (const float*)d_in[2];
  const int*   outcell   = (const int*)d_in[3];
  const float* Wq = (const float*)d_in[4];
  const float* bq = (const float*)d_in[5];
  const float* Wk = (const float*)d_in[6];
  const float* bk = (const float*)d_in[7];
  const float* Wv = (const float*)d_in[8];
  const float* bv = (const float*)d_in[9];
  const float* wf = (const float*)d_in[10];
  float* out = (float*)d_out;
  float* ws  = (float*)d_ws;

  // workspace layout (floats): ~2.87M floats = 11.5 MB
  float* wve = ws;                                  // 48*768
  float* ube = ws + 36864;                          // 48 (padded to 64)
  float* qsb = ws + 36928;                          // 2*512*768
  float* keb = qsb + (size_t)BDIM * NQ * ED;        // 2*48*16*768
  float* ubb = keb + (size_t)BDIM * HN * DD * MDIM; // 2*48*768
  float* Wb  = ubb + (size_t)BDIM * HN * MDIM;      // 2*512*768

  hipMemsetAsync(Wb, 0, (size_t)BDIM * NQ * MDIM * sizeof(float), stream);
  prep_kernel<<<HN, 256, 0, stream>>>(Wv, bv, wf, wve, ube);
  proj_kernel<<<dim3(25, 16), 256, 0, stream>>>(query, Wq, bq, Wk, bk, wve, ube,
                                                qsb, keb, ubb);
  gather_kernel<<<1632, 256, 0, stream>>>(outcell, keb, ubb);
  attn_kernel<<<768, 256, 0, stream>>>(qsb, keb, ubb, attn_bias, Wb);
  force_kernel<<<256, 256, 0, stream>>>(Wb, delta_pos, out);
}

// Round 3
// 403.179 us; speedup vs baseline: 2.3161x; 2.3161x over previous
//
#include <hip/hip_runtime.h>
#include <cstdint>
#include <cstddef>

#define BDIM 2
#define NQ 512
#define NEXP 256
#define MDIM 768
#define HN 48
#define DD 16
#define ED 768

// ---------------------------------------------------------------------------
// prep: wve[h][k] = sum_d w_force[h*16+d] * Wv[(h*16+d)*E + k]
//       ube[h]    = sum_d w_force[h*16+d] * bv[h*16+d]
// ---------------------------------------------------------------------------
__global__ void prep_kernel(const float* __restrict__ Wv, const float* __restrict__ bv,
                            const float* __restrict__ wf,
                            float* __restrict__ wve, float* __restrict__ ube) {
  int h = blockIdx.x;
  float wl[DD];
#pragma unroll
  for (int d = 0; d < DD; ++d) wl[d] = wf[h * DD + d];
  for (int k = threadIdx.x; k < ED; k += blockDim.x) {
    float s = 0.f;
#pragma unroll
    for (int d = 0; d < DD; ++d) s = fmaf(wl[d], Wv[(size_t)(h * DD + d) * ED + k], s);
    wve[(size_t)h * ED + k] = s;
  }
  if (threadIdx.x == 0) {
    float s = 0.f;
#pragma unroll
    for (int d = 0; d < DD; ++d) s = fmaf(wl[d], bv[h * DD + d], s);
    ube[h] = s;
  }
}

// ---------------------------------------------------------------------------
// proj: one GEMM out[1024 x 1584] = query[1024x768] @ [Wq; Wk; wve]^T
//   cols 0..767    -> qs[b][n][c]           = (dot + bq[c]) * 0.25
//   cols 768..1535 -> ke[(b*H+h)*16+d][n]   = dot + bk      (transposed k)
//   cols 1536..1583-> ub[(b*H+h)][n]        = dot + ube[h]
// ---------------------------------------------------------------------------
__global__ __launch_bounds__(256) void proj_kernel(
    const float* __restrict__ A,
    const float* __restrict__ Wq, const float* __restrict__ bq,
    const float* __restrict__ Wk, const float* __restrict__ bk,
    const float* __restrict__ wve, const float* __restrict__ ube,
    float* __restrict__ qs, float* __restrict__ ke, float* __restrict__ ub) {
  __shared__ __align__(16) float As[32][68];
  __shared__ __align__(16) float Bs[32][68];
  const int tid = threadIdx.x;
  const int tx = tid & 15, ty = tid >> 4;
  const int row0 = blockIdx.y * 64;
  const int col0 = blockIdx.x * 64;
  float acc[4][4] = {};
  for (int k0 = 0; k0 < ED; k0 += 32) {
    for (int f = tid; f < 512; f += 256) {
      int r = f >> 3, kq = f & 7;
      float4 v = *(const float4*)&A[(size_t)(row0 + r) * ED + k0 + kq * 4];
      As[kq * 4 + 0][r] = v.x; As[kq * 4 + 1][r] = v.y;
      As[kq * 4 + 2][r] = v.z; As[kq * 4 + 3][r] = v.w;
    }
    for (int f = tid; f < 512; f += 256) {
      int cc = f >> 3, kq = f & 7;
      int c = col0 + cc;
      float4 v = make_float4(0.f, 0.f, 0.f, 0.f);
      if (c < 1584) {
        const float* src;
        if (c < 768) src = Wq + (size_t)c * ED;
        else if (c < 1536) src = Wk + (size_t)(c - 768) * ED;
        else src = wve + (size_t)(c - 1536) * ED;
        v = *(const float4*)&src[k0 + kq * 4];
      }
      Bs[kq * 4 + 0][cc] = v.x; Bs[kq * 4 + 1][cc] = v.y;
      Bs[kq * 4 + 2][cc] = v.z; Bs[kq * 4 + 3][cc] = v.w;
    }
    __syncthreads();
#pragma unroll
    for (int kk = 0; kk < 32; ++kk) {
      float4 a4 = *(const float4*)&As[kk][ty * 4];
      float4 b4 = *(const float4*)&Bs[kk][tx * 4];
      float av[4] = {a4.x, a4.y, a4.z, a4.w};
      float bw[4] = {b4.x, b4.y, b4.z, b4.w};
#pragma unroll
      for (int i = 0; i < 4; ++i)
#pragma unroll
        for (int j = 0; j < 4; ++j) acc[i][j] = fmaf(av[i], bw[j], acc[i][j]);
    }
    __syncthreads();
  }
#pragma unroll
  for (int i = 0; i < 4; ++i) {
    int r = row0 + ty * 4 + i;
    int b = r >> 9, n = r & 511;
#pragma unroll
    for (int j = 0; j < 4; ++j) {
      int c = col0 + tx * 4 + j;
      if (c >= 1584) continue;
      float val = acc[i][j];
      if (c < 768) {
        qs[(size_t)(b * NQ + n) * ED + c] = (val + bq[c]) * 0.25f;
      } else if (c < 1536) {
        int ck = c - 768;
        int hh = ck >> 4, dd = ck & 15;
        ke[(size_t)((b * HN + hh) * DD + dd) * MDIM + n] = val + bk[ck];
      } else {
        int hh = c - 1536;
        ub[(size_t)(b * HN + hh) * MDIM + n] = val + ube[hh];
      }
    }
  }
}

// ---------------------------------------------------------------------------
// gather: fill m in [512,768) of ke / ub via outcell_index
// ---------------------------------------------------------------------------
__global__ void gather_kernel(const int* __restrict__ idx, float* __restrict__ ke,
                              float* __restrict__ ub) {
  const int id = blockIdx.x * 256 + threadIdx.x;
  const int N1 = BDIM * HN * DD * NEXP;  // 393216
  if (id < N1) {
    int j = id & (NEXP - 1);
    int d = (id >> 8) & (DD - 1);
    int hb = id >> 12;                   // b*48 + h, 0..95
    int n = idx[(hb / HN) * NEXP + j];
    float* row = ke + (size_t)(hb * DD + d) * MDIM;
    row[NQ + j] = row[n];
  } else {
    int id2 = id - N1;
    if (id2 < BDIM * HN * NEXP) {
      int j = id2 & (NEXP - 1);
      int hb = id2 >> 8;                 // b*48 + h
      int n = idx[(hb / HN) * NEXP + j];
      float* row = ub + (size_t)hb * MDIM;
      row[NQ + j] = row[n];
    }
  }
}

// ---------------------------------------------------------------------------
// fused attention+force: block = (b, 4 query rows). 4 waves, each wave owns
// 12 heads for the SAME 4 rows (full m-row in registers, K amortized over 4
// rows, read straight from the b-partitioned XCD L2). Per head: scores =
// bias + qK, wave-shuffle softmax, Wacc += e*u/l. Head-reduction across the
// 4 waves happens in LDS; force = sum_m W*dp finishes in-block. No atomics,
// no intermediate W traffic, dp read exactly once.
// ---------------------------------------------------------------------------
__device__ __forceinline__ void fma4(float4& a, float q, const float4& k) {
  a.x = fmaf(q, k.x, a.x); a.y = fmaf(q, k.y, a.y);
  a.z = fmaf(q, k.z, a.z); a.w = fmaf(q, k.w, a.w);
}

__global__ __launch_bounds__(256) void fused_kernel(
    const float* __restrict__ qs, const float* __restrict__ ke, const float* __restrict__ ub,
    const float* __restrict__ bias, const float* __restrict__ dp, float* __restrict__ out) {
  __shared__ __align__(16) float Wl[4][4][MDIM];   // [wave][row][m], 48 KB
  const int bid = blockIdx.x;
  const int b = bid & 1;                 // XCD parity: each XCD's L2 holds one b's K
  const int n0 = (bid >> 1) * 4;         // 4-row group
  const int wave = threadIdx.x >> 6;
  const int lane = threadIdx.x & 63;

  float4 wacc[4][3] = {};                // per-row partial W over this wave's 12 heads

  for (int hi = 0; hi < 12; ++hi) {
    const int h = wave * 12 + hi;
    const float* kbase = ke + (size_t)(b * HN + h) * DD * MDIM;
    const float4* u4 = (const float4*)(ub + (size_t)(b * HN + h) * MDIM);
    const float4 u0 = u4[lane], u1 = u4[lane + 64], u2 = u4[lane + 128];

    // scores init = bias rows (12 float4/lane per row covers full m)
    float4 a[4][3];
#pragma unroll
    for (int qi = 0; qi < 4; ++qi) {
      const float4* bp = (const float4*)(bias + (size_t)((b * HN + h) * NQ + n0 + qi) * MDIM);
#pragma unroll
      for (int j = 0; j < 3; ++j) a[qi][j] = bp[lane + 64 * j];
    }
    // scores += q_d * K[d][m]
#pragma unroll
    for (int x = 0; x < 4; ++x) {
      float4 qx[4];
#pragma unroll
      for (int qi = 0; qi < 4; ++qi)
        qx[qi] = ((const float4*)(qs + (size_t)(b * NQ + n0 + qi) * ED + h * DD))[x];
#pragma unroll
      for (int d4 = 0; d4 < 4; ++d4) {
        const float4* kr = (const float4*)(kbase + (size_t)(x * 4 + d4) * MDIM);
        const float4 k0 = kr[lane], k1 = kr[lane + 64], k2 = kr[lane + 128];
#pragma unroll
        for (int qi = 0; qi < 4; ++qi) {
          const float qd = (d4 == 0) ? qx[qi].x : (d4 == 1) ? qx[qi].y
                          : (d4 == 2) ? qx[qi].z : qx[qi].w;
          fma4(a[qi][0], qd, k0);
          fma4(a[qi][1], qd, k1);
          fma4(a[qi][2], qd, k2);
        }
      }
    }
    // softmax + accumulate W partial
#pragma unroll
    for (int qi = 0; qi < 4; ++qi) {
      float mx = -1e30f;
#pragma unroll
      for (int j = 0; j < 3; ++j)
        mx = fmaxf(mx, fmaxf(fmaxf(a[qi][j].x, a[qi][j].y), fmaxf(a[qi][j].z, a[qi][j].w)));
#pragma unroll
      for (int sh = 32; sh > 0; sh >>= 1) mx = fmaxf(mx, __shfl_xor(mx, sh));
      float e[12];
#pragma unroll
      for (int j = 0; j < 3; ++j) {
        e[j * 4 + 0] = __expf(a[qi][j].x - mx);
        e[j * 4 + 1] = __expf(a[qi][j].y - mx);
        e[j * 4 + 2] = __expf(a[qi][j].z - mx);
        e[j * 4 + 3] = __expf(a[qi][j].w - mx);
      }
      float l = 0.f;
#pragma unroll
      for (int k = 0; k < 12; ++k) l += e[k];
#pragma unroll
      for (int sh = 32; sh > 0; sh >>= 1) l += __shfl_xor(l, sh);
      const float inv = 1.0f / l;
#pragma unroll
      for (int j = 0; j < 3; ++j) {
        const float4 uu = (j == 0) ? u0 : (j == 1) ? u1 : u2;
        wacc[qi][j].x = fmaf(e[j * 4 + 0] * inv, uu.x, wacc[qi][j].x);
        wacc[qi][j].y = fmaf(e[j * 4 + 1] * inv, uu.y, wacc[qi][j].y);
        wacc[qi][j].z = fmaf(e[j * 4 + 2] * inv, uu.z, wacc[qi][j].z);
        wacc[qi][j].w = fmaf(e[j * 4 + 3] * inv, uu.w, wacc[qi][j].w);
      }
    }
  }

  // deposit per-wave partials, reduce across waves, finish force in-block
#pragma unroll
  for (int qi = 0; qi < 4; ++qi) {
    float4* dst = (float4*)Wl[wave][qi];
#pragma unroll
    for (int j = 0; j < 3; ++j) dst[lane + 64 * j] = wacc[qi][j];
  }
  __syncthreads();

  {
    const int qi = wave;  // each wave finishes one row
    float4 ws[3];
#pragma unroll
    for (int j = 0; j < 3; ++j) {
      const float4* r0 = (const float4*)Wl[0][qi];
      const float4* r1 = (const float4*)Wl[1][qi];
      const float4* r2 = (const float4*)Wl[2][qi];
      const float4* r3 = (const float4*)Wl[3][qi];
      float4 s = r0[lane + 64 * j];
      float4 t1 = r1[lane + 64 * j], t2 = r2[lane + 64 * j], t3 = r3[lane + 64 * j];
      s.x += t1.x + t2.x + t3.x; s.y += t1.y + t2.y + t3.y;
      s.z += t1.z + t2.z + t3.z; s.w += t1.w + t2.w + t3.w;
      ws[j] = s;
    }
    const float* dpp = dp + (size_t)(b * NQ + n0 + qi) * MDIM * 3;
    float f0 = 0.f, f1 = 0.f, f2 = 0.f;
#pragma unroll
    for (int j = 0; j < 3; ++j) {
      const float4 w = ws[j];
      const int m0 = j * 256 + lane * 4;
      const float4* dv = (const float4*)(dpp + (size_t)m0 * 3);
      const float4 d0 = dv[0], d1 = dv[1], d2 = dv[2];
      f0 = fmaf(w.x, d0.x, f0); f0 = fmaf(w.y, d0.w, f0); f0 = fmaf(w.z, d1.z, f0); f0 = fmaf(w.w, d2.y, f0);
      f1 = fmaf(w.x, d0.y, f1); f1 = fmaf(w.y, d1.x, f1); f1 = fmaf(w.z, d1.w, f1); f1 = fmaf(w.w, d2.z, f1);
      f2 = fmaf(w.x, d0.z, f2); f2 = fmaf(w.y, d1.y, f2); f2 = fmaf(w.z, d2.x, f2); f2 = fmaf(w.w, d2.w, f2);
    }
#pragma unroll
    for (int sh = 32; sh > 0; sh >>= 1) {
      f0 += __shfl_xor(f0, sh);
      f1 += __shfl_xor(f1, sh);
      f2 += __shfl_xor(f2, sh);
    }
    if (lane == 0) {
      float* op = out + (size_t)(b * NQ + n0 + qi) * 3;
      op[0] = f0; op[1] = f1; op[2] = f2;
    }
  }
}

// ---------------------------------------------------------------------------
extern "C" void kernel_launch(void* const* d_in, const int* in_sizes, int n_in,
                              void* d_out, int out_size, void* d_ws, size_t ws_size,
                              hipStream_t stream) {
  const float* query     = (const float*)d_in[0];
  const float* attn_bias = (const float*)d_in[1];
  const float* delta_pos = (const float*)d_in[2];
  const int*   outcell   = (const int*)d_in[3];
  const float* Wq = (const float*)d_in[4];
  const float* bq = (const float*)d_in[5];
  const float* Wk = (const float*)d_in[6];
  const float* bk = (const float*)d_in[7];
  const float* Wv = (const float*)d_in[8];
  const float* bv = (const float*)d_in[9];
  const float* wf = (const float*)d_in[10];
  float* out = (float*)d_out;
  float* ws  = (float*)d_ws;

  // workspace layout (floats): ~2.08M floats = 8.3 MB
  float* wve = ws;                                  // 48*768
  float* ube = ws + 36864;                          // 48 (padded to 64)
  float* qsb = ws + 36928;                          // 2*512*768
  float* keb = qsb + (size_t)BDIM * NQ * ED;        // 2*48*16*768
  float* ubb = keb + (size_t)BDIM * HN * DD * MDIM; // 2*48*768

  prep_kernel<<<HN, 256, 0, stream>>>(Wv, bv, wf, wve, ube);
  proj_kernel<<<dim3(25, 16), 256, 0, stream>>>(query, Wq, bq, Wk, bk, wve, ube,
                                                qsb, keb, ubb);
  gather_kernel<<<1632, 256, 0, stream>>>(outcell, keb, ubb);
  fused_kernel<<<256, 256, 0, stream>>>(qsb, keb, ubb, attn_bias, delta_pos, out);
}

// Round 4
// 395.615 us; speedup vs baseline: 2.3604x; 1.0191x over previous
//
#include <hip/hip_runtime.h>
#include <cstdint>
#include <cstddef>

#define BDIM 2
#define NQ 512
#define NEXP 256
#define MDIM 768
#define HN 48
#define DD 16
#define ED 768

// ---------------------------------------------------------------------------
// prep: wve[h][k] = sum_d w_force[h*16+d] * Wv[(h*16+d)*E + k]
//       ube[h]    = sum_d w_force[h*16+d] * bv[h*16+d]
// ---------------------------------------------------------------------------
__global__ void prep_kernel(const float* __restrict__ Wv, const float* __restrict__ bv,
                            const float* __restrict__ wf,
                            float* __restrict__ wve, float* __restrict__ ube) {
  int h = blockIdx.x;
  float wl[DD];
#pragma unroll
  for (int d = 0; d < DD; ++d) wl[d] = wf[h * DD + d];
  for (int k = threadIdx.x; k < ED; k += blockDim.x) {
    float s = 0.f;
#pragma unroll
    for (int d = 0; d < DD; ++d) s = fmaf(wl[d], Wv[(size_t)(h * DD + d) * ED + k], s);
    wve[(size_t)h * ED + k] = s;
  }
  if (threadIdx.x == 0) {
    float s = 0.f;
#pragma unroll
    for (int d = 0; d < DD; ++d) s = fmaf(wl[d], bv[h * DD + d], s);
    ube[h] = s;
  }
}

// ---------------------------------------------------------------------------
// proj: one GEMM out[1024 x 1584] = query[1024x768] @ [Wq; Wk; wve]^T
//   cols 0..767    -> qs[b][n][c]           = (dot + bq[c]) * 0.25
//   cols 768..1535 -> ke[(b*H+h)*16+d][n]   = dot + bk      (transposed k)
//   cols 1536..1583-> ub[(b*H+h)][n]        = dot + ube[h]
// ---------------------------------------------------------------------------
__global__ __launch_bounds__(256) void proj_kernel(
    const float* __restrict__ A,
    const float* __restrict__ Wq, const float* __restrict__ bq,
    const float* __restrict__ Wk, const float* __restrict__ bk,
    const float* __restrict__ wve, const float* __restrict__ ube,
    float* __restrict__ qs, float* __restrict__ ke, float* __restrict__ ub) {
  __shared__ __align__(16) float As[32][68];
  __shared__ __align__(16) float Bs[32][68];
  const int tid = threadIdx.x;
  const int tx = tid & 15, ty = tid >> 4;
  const int row0 = blockIdx.y * 64;
  const int col0 = blockIdx.x * 64;
  float acc[4][4] = {};
  for (int k0 = 0; k0 < ED; k0 += 32) {
    for (int f = tid; f < 512; f += 256) {
      int r = f >> 3, kq = f & 7;
      float4 v = *(const float4*)&A[(size_t)(row0 + r) * ED + k0 + kq * 4];
      As[kq * 4 + 0][r] = v.x; As[kq * 4 + 1][r] = v.y;
      As[kq * 4 + 2][r] = v.z; As[kq * 4 + 3][r] = v.w;
    }
    for (int f = tid; f < 512; f += 256) {
      int cc = f >> 3, kq = f & 7;
      int c = col0 + cc;
      float4 v = make_float4(0.f, 0.f, 0.f, 0.f);
      if (c < 1584) {
        const float* src;
        if (c < 768) src = Wq + (size_t)c * ED;
        else if (c < 1536) src = Wk + (size_t)(c - 768) * ED;
        else src = wve + (size_t)(c - 1536) * ED;
        v = *(const float4*)&src[k0 + kq * 4];
      }
      Bs[kq * 4 + 0][cc] = v.x; Bs[kq * 4 + 1][cc] = v.y;
      Bs[kq * 4 + 2][cc] = v.z; Bs[kq * 4 + 3][cc] = v.w;
    }
    __syncthreads();
#pragma unroll
    for (int kk = 0; kk < 32; ++kk) {
      float4 a4 = *(const float4*)&As[kk][ty * 4];
      float4 b4 = *(const float4*)&Bs[kk][tx * 4];
      float av[4] = {a4.x, a4.y, a4.z, a4.w};
      float bw[4] = {b4.x, b4.y, b4.z, b4.w};
#pragma unroll
      for (int i = 0; i < 4; ++i)
#pragma unroll
        for (int j = 0; j < 4; ++j) acc[i][j] = fmaf(av[i], bw[j], acc[i][j]);
    }
    __syncthreads();
  }
#pragma unroll
  for (int i = 0; i < 4; ++i) {
    int r = row0 + ty * 4 + i;
    int b = r >> 9, n = r & 511;
#pragma unroll
    for (int j = 0; j < 4; ++j) {
      int c = col0 + tx * 4 + j;
      if (c >= 1584) continue;
      float val = acc[i][j];
      if (c < 768) {
        qs[(size_t)(b * NQ + n) * ED + c] = (val + bq[c]) * 0.25f;
      } else if (c < 1536) {
        int ck = c - 768;
        int hh = ck >> 4, dd = ck & 15;
        ke[(size_t)((b * HN + hh) * DD + dd) * MDIM + n] = val + bk[ck];
      } else {
        int hh = c - 1536;
        ub[(size_t)(b * HN + hh) * MDIM + n] = val + ube[hh];
      }
    }
  }
}

// ---------------------------------------------------------------------------
// gather: fill m in [512,768) of ke / ub via outcell_index
// ---------------------------------------------------------------------------
__global__ void gather_kernel(const int* __restrict__ idx, float* __restrict__ ke,
                              float* __restrict__ ub) {
  const int id = blockIdx.x * 256 + threadIdx.x;
  const int N1 = BDIM * HN * DD * NEXP;  // 393216
  if (id < N1) {
    int j = id & (NEXP - 1);
    int d = (id >> 8) & (DD - 1);
    int hb = id >> 12;                   // b*48 + h, 0..95
    int n = idx[(hb / HN) * NEXP + j];
    float* row = ke + (size_t)(hb * DD + d) * MDIM;
    row[NQ + j] = row[n];
  } else {
    int id2 = id - N1;
    if (id2 < BDIM * HN * NEXP) {
      int j = id2 & (NEXP - 1);
      int hb = id2 >> 8;                 // b*48 + h
      int n = idx[(hb / HN) * NEXP + j];
      float* row = ub + (size_t)hb * MDIM;
      row[NQ + j] = row[n];
    }
  }
}

// ---------------------------------------------------------------------------
// fused attention: block = (b, head-group of 12, 4 query rows). 4 waves x 3
// heads each; per head: scores = bias + qK (full m-row in registers, K from
// the XCD-pinned L2), wave-shuffle softmax, wacc += e*u/l. Cross-wave
// reduce in 24 KB LDS (two-phase float4 adds, contiguous = conflict-free),
// then one fp32 partial W per (row, hg) to global. No atomics.
// bid%8 == (hg,b): each XCD's L2 keeps one (hg,b)'s K (576 KB).
// ---------------------------------------------------------------------------
__device__ __forceinline__ void fma4(float4& a, float q, const float4& k) {
  a.x = fmaf(q, k.x, a.x); a.y = fmaf(q, k.y, a.y);
  a.z = fmaf(q, k.z, a.z); a.w = fmaf(q, k.w, a.w);
}

__global__ __launch_bounds__(256) void fused_kernel(
    const float* __restrict__ qs, const float* __restrict__ ke, const float* __restrict__ ub,
    const float* __restrict__ bias, float* __restrict__ Wp) {
  __shared__ __align__(16) float Wl[2][4 * MDIM];  // 24 KB
  const int bid = blockIdx.x;
  const int b = bid & 1;
  const int hg = (bid >> 1) & 3;
  const int n0 = (bid >> 3) * 4;
  const int wave = threadIdx.x >> 6;
  const int lane = threadIdx.x & 63;

  float4 wacc[4][3] = {};   // per-row partial W over this wave's 3 heads

  for (int hi = 0; hi < 3; ++hi) {
    const int h = hg * 12 + wave * 3 + hi;
    const float* kbase = ke + (size_t)(b * HN + h) * DD * MDIM;
    const float4* u4 = (const float4*)(ub + (size_t)(b * HN + h) * MDIM);
    const float4 u0 = u4[lane], u1 = u4[lane + 64], u2 = u4[lane + 128];

    float4 a[4][3];
#pragma unroll
    for (int qi = 0; qi < 4; ++qi) {
      const float4* bp = (const float4*)(bias + (size_t)((b * HN + h) * NQ + n0 + qi) * MDIM);
#pragma unroll
      for (int j = 0; j < 3; ++j) a[qi][j] = bp[lane + 64 * j];
    }
#pragma unroll
    for (int x = 0; x < 4; ++x) {
      float4 qx[4];
#pragma unroll
      for (int qi = 0; qi < 4; ++qi)
        qx[qi] = ((const float4*)(qs + (size_t)(b * NQ + n0 + qi) * ED + h * DD))[x];
#pragma unroll
      for (int d4 = 0; d4 < 4; ++d4) {
        const float4* kr = (const float4*)(kbase + (size_t)(x * 4 + d4) * MDIM);
        const float4 k0 = kr[lane], k1 = kr[lane + 64], k2 = kr[lane + 128];
#pragma unroll
        for (int qi = 0; qi < 4; ++qi) {
          const float qd = (d4 == 0) ? qx[qi].x : (d4 == 1) ? qx[qi].y
                          : (d4 == 2) ? qx[qi].z : qx[qi].w;
          fma4(a[qi][0], qd, k0);
          fma4(a[qi][1], qd, k1);
          fma4(a[qi][2], qd, k2);
        }
      }
    }
#pragma unroll
    for (int qi = 0; qi < 4; ++qi) {
      float mx = -1e30f;
#pragma unroll
      for (int j = 0; j < 3; ++j)
        mx = fmaxf(mx, fmaxf(fmaxf(a[qi][j].x, a[qi][j].y), fmaxf(a[qi][j].z, a[qi][j].w)));
#pragma unroll
      for (int sh = 32; sh > 0; sh >>= 1) mx = fmaxf(mx, __shfl_xor(mx, sh));
      float e[12];
#pragma unroll
      for (int j = 0; j < 3; ++j) {
        e[j * 4 + 0] = __expf(a[qi][j].x - mx);
        e[j * 4 + 1] = __expf(a[qi][j].y - mx);
        e[j * 4 + 2] = __expf(a[qi][j].z - mx);
        e[j * 4 + 3] = __expf(a[qi][j].w - mx);
      }
      float l = 0.f;
#pragma unroll
      for (int k = 0; k < 12; ++k) l += e[k];
#pragma unroll
      for (int sh = 32; sh > 0; sh >>= 1) l += __shfl_xor(l, sh);
      const float inv = 1.0f / l;
#pragma unroll
      for (int j = 0; j < 3; ++j) {
        const float4 uu = (j == 0) ? u0 : (j == 1) ? u1 : u2;
        wacc[qi][j].x = fmaf(e[j * 4 + 0] * inv, uu.x, wacc[qi][j].x);
        wacc[qi][j].y = fmaf(e[j * 4 + 1] * inv, uu.y, wacc[qi][j].y);
        wacc[qi][j].z = fmaf(e[j * 4 + 2] * inv, uu.z, wacc[qi][j].z);
        wacc[qi][j].w = fmaf(e[j * 4 + 3] * inv, uu.w, wacc[qi][j].w);
      }
    }
  }

  // two-phase cross-wave reduce in LDS (contiguous float4 -> conflict-free)
  if (wave >= 2) {
    float4* dst = (float4*)Wl[wave - 2];
#pragma unroll
    for (int qi = 0; qi < 4; ++qi)
#pragma unroll
      for (int j = 0; j < 3; ++j) dst[qi * 192 + lane + 64 * j] = wacc[qi][j];
  }
  __syncthreads();
  if (wave < 2) {
    float4* dst = (float4*)Wl[wave];
#pragma unroll
    for (int qi = 0; qi < 4; ++qi)
#pragma unroll
      for (int j = 0; j < 3; ++j) {
        float4 t = dst[qi * 192 + lane + 64 * j];
        t.x += wacc[qi][j].x; t.y += wacc[qi][j].y;
        t.z += wacc[qi][j].z; t.w += wacc[qi][j].w;
        dst[qi * 192 + lane + 64 * j] = t;
      }
  }
  __syncthreads();

  // write partial W: Wp[((b*NQ+n)*4 + hg)*192 + mf] (float4 units)
  const float4* w0 = (const float4*)Wl[0];
  const float4* w1 = (const float4*)Wl[1];
  float4* wp = (float4*)Wp;
  for (int f = threadIdx.x; f < 768; f += 256) {
    const int qi = f / 192, mf = f % 192;
    float4 s = w0[f];
    const float4 t = w1[f];
    s.x += t.x; s.y += t.y; s.z += t.z; s.w += t.w;
    wp[((size_t)(b * NQ + n0 + qi) * 4 + hg) * 192 + mf] = s;
  }
}

// ---------------------------------------------------------------------------
// force: sum the 4 hg-partials of W, then force[row,c] = sum_m W*dp.
// One wave per (b,n) row.
// ---------------------------------------------------------------------------
__global__ __launch_bounds__(256) void force_kernel(
    const float* __restrict__ Wp, const float* __restrict__ dp, float* __restrict__ out) {
  const int wave = threadIdx.x >> 6;
  const int lane = threadIdx.x & 63;
  const int row = blockIdx.x * 4 + wave;     // 0..1023 == b*512+n
  const float4* wp = (const float4*)Wp;
  float4 ws[3];
#pragma unroll
  for (int j = 0; j < 3; ++j) {
    float4 s = wp[((size_t)row * 4 + 0) * 192 + lane + 64 * j];
#pragma unroll
    for (int hg = 1; hg < 4; ++hg) {
      const float4 t = wp[((size_t)row * 4 + hg) * 192 + lane + 64 * j];
      s.x += t.x; s.y += t.y; s.z += t.z; s.w += t.w;
    }
    ws[j] = s;
  }
  const float* dpp = dp + (size_t)row * MDIM * 3;
  float f0 = 0.f, f1 = 0.f, f2 = 0.f;
#pragma unroll
  for (int j = 0; j < 3; ++j) {
    const float4 w = ws[j];
    const int m0 = j * 256 + lane * 4;
    const float4* dv = (const float4*)(dpp + (size_t)m0 * 3);
    const float4 d0 = dv[0], d1 = dv[1], d2 = dv[2];
    f0 = fmaf(w.x, d0.x, f0); f0 = fmaf(w.y, d0.w, f0); f0 = fmaf(w.z, d1.z, f0); f0 = fmaf(w.w, d2.y, f0);
    f1 = fmaf(w.x, d0.y, f1); f1 = fmaf(w.y, d1.x, f1); f1 = fmaf(w.z, d1.w, f1); f1 = fmaf(w.w, d2.z, f1);
    f2 = fmaf(w.x, d0.z, f2); f2 = fmaf(w.y, d1.y, f2); f2 = fmaf(w.z, d2.x, f2); f2 = fmaf(w.w, d2.w, f2);
  }
#pragma unroll
  for (int sh = 32; sh > 0; sh >>= 1) {
    f0 += __shfl_xor(f0, sh);
    f1 += __shfl_xor(f1, sh);
    f2 += __shfl_xor(f2, sh);
  }
  if (lane == 0) {
    float* op = out + (size_t)row * 3;
    op[0] = f0; op[1] = f1; op[2] = f2;
  }
}

// ---------------------------------------------------------------------------
extern "C" void kernel_launch(void* const* d_in, const int* in_sizes, int n_in,
                              void* d_out, int out_size, void* d_ws, size_t ws_size,
                              hipStream_t stream) {
  const float* query     = (const float*)d_in[0];
  const float* attn_bias = (const float*)d_in[1];
  const float* delta_pos = (const float*)d_in[2];
  const int*   outcell   = (const int*)d_in[3];
  const float* Wq = (const float*)d_in[4];
  const float* bq = (const float*)d_in[5];
  const float* Wk = (const float*)d_in[6];
  const float* bk = (const float*)d_in[7];
  const float* Wv = (const float*)d_in[8];
  const float* bv = (const float*)d_in[9];
  const float* wf = (const float*)d_in[10];
  float* out = (float*)d_out;
  float* ws  = (float*)d_ws;

  // workspace layout (floats): ~5.2M floats = 21 MB
  float* wve = ws;                                  // 48*768
  float* ube = ws + 36864;                          // 48 (padded to 64)
  float* qsb = ws + 36928;                          // 2*512*768
  float* keb = qsb + (size_t)BDIM * NQ * ED;        // 2*48*16*768
  float* ubb = keb + (size_t)BDIM * HN * DD * MDIM; // 2*48*768
  float* Wpb = ubb + (size_t)BDIM * HN * MDIM;      // 2*512*4*768 = 3.1M

  prep_kernel<<<HN, 256, 0, stream>>>(Wv, bv, wf, wve, ube);
  proj_kernel<<<dim3(25, 16), 256, 0, stream>>>(query, Wq, bq, Wk, bk, wve, ube,
                                                qsb, keb, ubb);
  gather_kernel<<<1632, 256, 0, stream>>>(outcell, keb, ubb);
  fused_kernel<<<1024, 256, 0, stream>>>(qsb, keb, ubb, attn_bias, Wpb);
  force_kernel<<<256, 256, 0, stream>>>(Wpb, delta_pos, out);
}

// Round 5
// 316.075 us; speedup vs baseline: 2.9544x; 1.2517x over previous
//
#include <hip/hip_runtime.h>
#include <cstdint>
#include <cstddef>

#define BDIM 2
#define NQ 512
#define NEXP 256
#define MDIM 768
#define HN 48
#define DD 16
#define ED 768

typedef short v8s __attribute__((ext_vector_type(8)));
typedef float v4f __attribute__((ext_vector_type(4)));

// ---------------------------------------------------------------------------
// prep: wve[h][k] = sum_d w_force[h*16+d] * Wv[(h*16+d)*E + k]
//       ube[h]    = sum_d w_force[h*16+d] * bv[h*16+d]
// ---------------------------------------------------------------------------
__global__ void prep_kernel(const float* __restrict__ Wv, const float* __restrict__ bv,
                            const float* __restrict__ wf,
                            float* __restrict__ wve, float* __restrict__ ube) {
  int h = blockIdx.x;
  float wl[DD];
#pragma unroll
  for (int d = 0; d < DD; ++d) wl[d] = wf[h * DD + d];
  for (int k = threadIdx.x; k < ED; k += blockDim.x) {
    float s = 0.f;
#pragma unroll
    for (int d = 0; d < DD; ++d) s = fmaf(wl[d], Wv[(size_t)(h * DD + d) * ED + k], s);
    wve[(size_t)h * ED + k] = s;
  }
  if (threadIdx.x == 0) {
    float s = 0.f;
#pragma unroll
    for (int d = 0; d < DD; ++d) s = fmaf(wl[d], bv[h * DD + d], s);
    ube[h] = s;
  }
}

// ---------------------------------------------------------------------------
// convert: fp32 -> bf16 (RNE). A = query (1024x768). B = [Wq;Wk;wve] padded
// to 1600 rows x 768 (rows >=1584 zeroed; their GEMM outputs are never stored).
// ---------------------------------------------------------------------------
__global__ __launch_bounds__(256) void convert_kernel(
    const float* __restrict__ query, const float* __restrict__ Wq,
    const float* __restrict__ Wk, const float* __restrict__ wve,
    ushort* __restrict__ Abf, ushort* __restrict__ Bbf) {
  const int id = blockIdx.x * 256 + threadIdx.x;   // 984*256 = 251904 exact
  const float* src = nullptr;
  ushort* dst;
  if (id < 98304) {                   // A: 786432/8 chunks
    const int off = id * 8;
    src = query + off;
    dst = Abf + off;
  } else {
    const int id2 = id - 98304;       // < 153600
    const int r = id2 / 96;
    const int k = (id2 - r * 96) * 8;
    dst = Bbf + (size_t)r * 768 + k;
    if (r < 768)       src = Wq + (size_t)r * 768 + k;
    else if (r < 1536) src = Wk + (size_t)(r - 768) * 768 + k;
    else if (r < 1584) src = wve + (size_t)(r - 1536) * 768 + k;
  }
  union { ushort s[8]; uint4 v; } p;
  if (src) {
    const float4 v0 = *(const float4*)src;
    const float4 v1 = *(const float4*)(src + 4);
    const float vv[8] = {v0.x, v0.y, v0.z, v0.w, v1.x, v1.y, v1.z, v1.w};
#pragma unroll
    for (int i = 0; i < 8; ++i) {
      union { float f; uint32_t u; } c; c.f = vv[i];
      p.s[i] = (ushort)((c.u + 0x7FFFu + ((c.u >> 16) & 1u)) >> 16);
    }
  } else {
#pragma unroll
    for (int i = 0; i < 8; ++i) p.s[i] = 0;
  }
  *(uint4*)dst = p.v;
}

// ---------------------------------------------------------------------------
// proj_mfma: C[1024 x 1600] = A_bf16[1024x768] @ B_bf16[1600x768]^T via
// v_mfma_f32_16x16x32_bf16. Block 256 thr / 4 waves; tile 64x64; wave w owns
// rows [w*16,w*16+16) x 64 cols = 4 MFMA tiles. LDS fragments stored in the
// exact per-lane-16B order the wave consumes (conflict-free ds_read_b128).
// Epilogue scatter identical to the old fp32 proj:
//   c<768 -> qs (bias+scale), c<1536 -> ke transposed, c<1584 -> ub.
// A-frag: A[m=lane&15][k=(lane>>4)*8+j]; C/D: col=lane&15, row=(lane>>4)*4+reg
// (verified layouts, learn_hip m89/m91).
// ---------------------------------------------------------------------------
__global__ __launch_bounds__(256) void proj_mfma(
    const ushort* __restrict__ Abf, const ushort* __restrict__ Bbf,
    const float* __restrict__ bq, const float* __restrict__ bk,
    const float* __restrict__ ube,
    float* __restrict__ qs, float* __restrict__ ke, float* __restrict__ ub) {
  __shared__ __align__(16) ushort As[4][4][16][8];  // [wave][kgrp][m][j] 4 KB
  __shared__ __align__(16) ushort Bs[4][64][8];     // [kgrp][n][j]       4 KB
  const int tid = threadIdx.x;
  const int wave = tid >> 6, lane = tid & 63;
  const int m0 = blockIdx.y * 64, n0 = blockIdx.x * 64;
  const int arow = tid >> 2;    // 0..63
  const int aseg = tid & 3;     // k-group 0..3
  v4f acc[4] = {v4f{0,0,0,0}, v4f{0,0,0,0}, v4f{0,0,0,0}, v4f{0,0,0,0}};

  for (int k0 = 0; k0 < ED; k0 += 32) {
    __syncthreads();
    *(uint4*)&As[arow >> 4][aseg][arow & 15][0] =
        *(const uint4*)&Abf[(size_t)(m0 + arow) * ED + k0 + aseg * 8];
    *(uint4*)&Bs[aseg][arow][0] =
        *(const uint4*)&Bbf[(size_t)(n0 + arow) * ED + k0 + aseg * 8];
    __syncthreads();
    const v8s af = *(const v8s*)&As[wave][lane >> 4][lane & 15][0];
#pragma unroll
    for (int nt = 0; nt < 4; ++nt) {
      const v8s bfr = *(const v8s*)&Bs[lane >> 4][nt * 16 + (lane & 15)][0];
      acc[nt] = __builtin_amdgcn_mfma_f32_16x16x32_bf16(af, bfr, acc[nt], 0, 0, 0);
    }
  }

#pragma unroll
  for (int nt = 0; nt < 4; ++nt) {
    const int c = n0 + nt * 16 + (lane & 15);
    if (c >= 1584) continue;
#pragma unroll
    for (int r = 0; r < 4; ++r) {
      const int row = m0 + wave * 16 + (lane >> 4) * 4 + r;
      const int b = row >> 9, n = row & 511;
      const float val = acc[nt][r];
      if (c < 768) {
        qs[(size_t)(b * NQ + n) * ED + c] = (val + bq[c]) * 0.25f;
      } else if (c < 1536) {
        const int ck = c - 768;
        const int hh = ck >> 4, dd = ck & 15;
        ke[(size_t)((b * HN + hh) * DD + dd) * MDIM + n] = val + bk[ck];
      } else {
        const int hh = c - 1536;
        ub[(size_t)(b * HN + hh) * MDIM + n] = val + ube[hh];
      }
    }
  }
}

// ---------------------------------------------------------------------------
// gather: fill m in [512,768) of ke / ub via outcell_index
// ---------------------------------------------------------------------------
__global__ void gather_kernel(const int* __restrict__ idx, float* __restrict__ ke,
                              float* __restrict__ ub) {
  const int id = blockIdx.x * 256 + threadIdx.x;
  const int N1 = BDIM * HN * DD * NEXP;  // 393216
  if (id < N1) {
    int j = id & (NEXP - 1);
    int d = (id >> 8) & (DD - 1);
    int hb = id >> 12;                   // b*48 + h, 0..95
    int n = idx[(hb / HN) * NEXP + j];
    float* row = ke + (size_t)(hb * DD + d) * MDIM;
    row[NQ + j] = row[n];
  } else {
    int id2 = id - N1;
    if (id2 < BDIM * HN * NEXP) {
      int j = id2 & (NEXP - 1);
      int hb = id2 >> 8;                 // b*48 + h
      int n = idx[(hb / HN) * NEXP + j];
      float* row = ub + (size_t)hb * MDIM;
      row[NQ + j] = row[n];
    }
  }
}

// ---------------------------------------------------------------------------
// fused attention: same decomposition as round 4 (block = b, hg of 12 heads,
// 4 query rows; 4 waves x 3 heads), ONE change: bias for head h+1 is
// prefetched into a[qi][] right after head h's softmax consumes a[qi] —
// the qK-FMA chain no longer stalls ~900 cyc on L2-missing bias loads.
// ---------------------------------------------------------------------------
__device__ __forceinline__ void fma4(float4& a, float q, const float4& k) {
  a.x = fmaf(q, k.x, a.x); a.y = fmaf(q, k.y, a.y);
  a.z = fmaf(q, k.z, a.z); a.w = fmaf(q, k.w, a.w);
}

__global__ __launch_bounds__(256) void fused_kernel(
    const float* __restrict__ qs, const float* __restrict__ ke, const float* __restrict__ ub,
    const float* __restrict__ bias, float* __restrict__ Wp) {
  __shared__ __align__(16) float Wl[2][4 * MDIM];  // 24 KB
  const int bid = blockIdx.x;
  const int b = bid & 1;
  const int hg = (bid >> 1) & 3;
  const int n0 = (bid >> 3) * 4;
  const int wave = threadIdx.x >> 6;
  const int lane = threadIdx.x & 63;
  const int hbase = hg * 12 + wave * 3;

  float4 wacc[4][3] = {};   // per-row partial W over this wave's 3 heads
  float4 a[4][3];

  // prefetch first head's bias
#pragma unroll
  for (int qi = 0; qi < 4; ++qi) {
    const float4* bp = (const float4*)(bias + (size_t)((b * HN + hbase) * NQ + n0 + qi) * MDIM);
#pragma unroll
    for (int j = 0; j < 3; ++j) a[qi][j] = bp[lane + 64 * j];
  }

  for (int hi = 0; hi < 3; ++hi) {
    const int h = hbase + hi;
    const float* kbase = ke + (size_t)(b * HN + h) * DD * MDIM;
    const float4* u4 = (const float4*)(ub + (size_t)(b * HN + h) * MDIM);
    const float4 u0 = u4[lane], u1 = u4[lane + 64], u2 = u4[lane + 128];

    // scores: a (holds prefetched bias) += q_d * K[d][m]
#pragma unroll
    for (int x = 0; x < 4; ++x) {
      float4 qx[4];
#pragma unroll
      for (int qi = 0; qi < 4; ++qi)
        qx[qi] = ((const float4*)(qs + (size_t)(b * NQ + n0 + qi) * ED + h * DD))[x];
#pragma unroll
      for (int d4 = 0; d4 < 4; ++d4) {
        const float4* kr = (const float4*)(kbase + (size_t)(x * 4 + d4) * MDIM);
        const float4 k0 = kr[lane], k1 = kr[lane + 64], k2 = kr[lane + 128];
#pragma unroll
        for (int qi = 0; qi < 4; ++qi) {
          const float qd = (d4 == 0) ? qx[qi].x : (d4 == 1) ? qx[qi].y
                          : (d4 == 2) ? qx[qi].z : qx[qi].w;
          fma4(a[qi][0], qd, k0);
          fma4(a[qi][1], qd, k1);
          fma4(a[qi][2], qd, k2);
        }
      }
    }
#pragma unroll
    for (int qi = 0; qi < 4; ++qi) {
      float mx = -1e30f;
#pragma unroll
      for (int j = 0; j < 3; ++j)
        mx = fmaxf(mx, fmaxf(fmaxf(a[qi][j].x, a[qi][j].y), fmaxf(a[qi][j].z, a[qi][j].w)));
#pragma unroll
      for (int sh = 32; sh > 0; sh >>= 1) mx = fmaxf(mx, __shfl_xor(mx, sh));
      float e[12];
#pragma unroll
      for (int j = 0; j < 3; ++j) {
        e[j * 4 + 0] = __expf(a[qi][j].x - mx);
        e[j * 4 + 1] = __expf(a[qi][j].y - mx);
        e[j * 4 + 2] = __expf(a[qi][j].z - mx);
        e[j * 4 + 3] = __expf(a[qi][j].w - mx);
      }
      // a[qi] is dead now: prefetch next head's bias row qi (hides ~900 cyc)
      if (hi < 2) {
        const float4* bp = (const float4*)(bias + (size_t)((b * HN + h + 1) * NQ + n0 + qi) * MDIM);
#pragma unroll
        for (int j = 0; j < 3; ++j) a[qi][j] = bp[lane + 64 * j];
      }
      float l = 0.f;
#pragma unroll
      for (int k = 0; k < 12; ++k) l += e[k];
#pragma unroll
      for (int sh = 32; sh > 0; sh >>= 1) l += __shfl_xor(l, sh);
      const float inv = 1.0f / l;
#pragma unroll
      for (int j = 0; j < 3; ++j) {
        const float4 uu = (j == 0) ? u0 : (j == 1) ? u1 : u2;
        wacc[qi][j].x = fmaf(e[j * 4 + 0] * inv, uu.x, wacc[qi][j].x);
        wacc[qi][j].y = fmaf(e[j * 4 + 1] * inv, uu.y, wacc[qi][j].y);
        wacc[qi][j].z = fmaf(e[j * 4 + 2] * inv, uu.z, wacc[qi][j].z);
        wacc[qi][j].w = fmaf(e[j * 4 + 3] * inv, uu.w, wacc[qi][j].w);
      }
    }
  }

  // two-phase cross-wave reduce in LDS (contiguous float4 -> conflict-free)
  if (wave >= 2) {
    float4* dst = (float4*)Wl[wave - 2];
#pragma unroll
    for (int qi = 0; qi < 4; ++qi)
#pragma unroll
      for (int j = 0; j < 3; ++j) dst[qi * 192 + lane + 64 * j] = wacc[qi][j];
  }
  __syncthreads();
  if (wave < 2) {
    float4* dst = (float4*)Wl[wave];
#pragma unroll
    for (int qi = 0; qi < 4; ++qi)
#pragma unroll
      for (int j = 0; j < 3; ++j) {
        float4 t = dst[qi * 192 + lane + 64 * j];
        t.x += wacc[qi][j].x; t.y += wacc[qi][j].y;
        t.z += wacc[qi][j].z; t.w += wacc[qi][j].w;
        dst[qi * 192 + lane + 64 * j] = t;
      }
  }
  __syncthreads();

  // write partial W: Wp[((b*NQ+n)*4 + hg)*192 + mf] (float4 units)
  const float4* w0 = (const float4*)Wl[0];
  const float4* w1 = (const float4*)Wl[1];
  float4* wp = (float4*)Wp;
  for (int f = threadIdx.x; f < 768; f += 256) {
    const int qi = f / 192, mf = f % 192;
    float4 s = w0[f];
    const float4 t = w1[f];
    s.x += t.x; s.y += t.y; s.z += t.z; s.w += t.w;
    wp[((size_t)(b * NQ + n0 + qi) * 4 + hg) * 192 + mf] = s;
  }
}

// ---------------------------------------------------------------------------
// force: sum the 4 hg-partials of W, then force[row,c] = sum_m W*dp.
// One wave per (b,n) row.
// ---------------------------------------------------------------------------
__global__ __launch_bounds__(256) void force_kernel(
    const float* __restrict__ Wp, const float* __restrict__ dp, float* __restrict__ out) {
  const int wave = threadIdx.x >> 6;
  const int lane = threadIdx.x & 63;
  const int row = blockIdx.x * 4 + wave;     // 0..1023 == b*512+n
  const float4* wp = (const float4*)Wp;
  float4 ws[3];
#pragma unroll
  for (int j = 0; j < 3; ++j) {
    float4 s = wp[((size_t)row * 4 + 0) * 192 + lane + 64 * j];
#pragma unroll
    for (int hg = 1; hg < 4; ++hg) {
      const float4 t = wp[((size_t)row * 4 + hg) * 192 + lane + 64 * j];
      s.x += t.x; s.y += t.y; s.z += t.z; s.w += t.w;
    }
    ws[j] = s;
  }
  const float* dpp = dp + (size_t)row * MDIM * 3;
  float f0 = 0.f, f1 = 0.f, f2 = 0.f;
#pragma unroll
  for (int j = 0; j < 3; ++j) {
    const float4 w = ws[j];
    const int m0 = j * 256 + lane * 4;
    const float4* dv = (const float4*)(dpp + (size_t)m0 * 3);
    const float4 d0 = dv[0], d1 = dv[1], d2 = dv[2];
    f0 = fmaf(w.x, d0.x, f0); f0 = fmaf(w.y, d0.w, f0); f0 = fmaf(w.z, d1.z, f0); f0 = fmaf(w.w, d2.y, f0);
    f1 = fmaf(w.x, d0.y, f1); f1 = fmaf(w.y, d1.x, f1); f1 = fmaf(w.z, d1.w, f1); f1 = fmaf(w.w, d2.z, f1);
    f2 = fmaf(w.x, d0.z, f2); f2 = fmaf(w.y, d1.y, f2); f2 = fmaf(w.z, d2.x, f2); f2 = fmaf(w.w, d2.w, f2);
  }
#pragma unroll
  for (int sh = 32; sh > 0; sh >>= 1) {
    f0 += __shfl_xor(f0, sh);
    f1 += __shfl_xor(f1, sh);
    f2 += __shfl_xor(f2, sh);
  }
  if (lane == 0) {
    float* op = out + (size_t)row * 3;
    op[0] = f0; op[1] = f1; op[2] = f2;
  }
}

// ---------------------------------------------------------------------------
extern "C" void kernel_launch(void* const* d_in, const int* in_sizes, int n_in,
                              void* d_out, int out_size, void* d_ws, size_t ws_size,
                              hipStream_t stream) {
  const float* query     = (const float*)d_in[0];
  const float* attn_bias = (const float*)d_in[1];
  const float* delta_pos = (const float*)d_in[2];
  const int*   outcell   = (const int*)d_in[3];
  const float* Wq = (const float*)d_in[4];
  const float* bq = (const float*)d_in[5];
  const float* Wk = (const float*)d_in[6];
  const float* bk = (const float*)d_in[7];
  const float* Wv = (const float*)d_in[8];
  const float* bv = (const float*)d_in[9];
  const float* wf = (const float*)d_in[10];
  float* out = (float*)d_out;
  float* ws  = (float*)d_ws;

  // workspace layout (float offsets, all 16B-aligned): total 6,230,080 fl ~ 24.9 MB
  float* wve  = ws;                       // 36864
  float* ube  = ws + 36864;               // 64
  float* qsb  = ws + 36928;               // 786432
  float* keb  = ws + 823360;              // 1179648
  float* ubb  = ws + 2003008;             // 73728
  float* Wpb  = ws + 2076736;             // 3145728
  ushort* Abf = (ushort*)(ws + 5222464);  // 786432 bf16
  ushort* Bbf = (ushort*)(ws + 5615680);  // 1228800 bf16 (1600x768)

  prep_kernel<<<HN, 256, 0, stream>>>(Wv, bv, wf, wve, ube);
  convert_kernel<<<984, 256, 0, stream>>>(query, Wq, Wk, wve, Abf, Bbf);
  proj_mfma<<<dim3(25, 16), 256, 0, stream>>>(Abf, Bbf, bq, bk, ube, qsb, keb, ubb);
  gather_kernel<<<1632, 256, 0, stream>>>(outcell, keb, ubb);
  fused_kernel<<<1024, 256, 0, stream>>>(qsb, keb, ubb, attn_bias, Wpb);
  force_kernel<<<256, 256, 0, stream>>>(Wpb, delta_pos, out);
}